// Round 5
// baseline (218.868 us; speedup 1.0000x reference)
//
#include <hip/hip_runtime.h>
#include <hip/hip_bf16.h>

typedef unsigned short u16;
typedef short short8 __attribute__((ext_vector_type(8)));
typedef float f32x4 __attribute__((ext_vector_type(4)));

// ---------------- helpers ----------------
static __device__ __forceinline__ u16 f2bf(float f) {
  unsigned u = __builtin_bit_cast(unsigned, f);
  unsigned r = (u + 0x7fffu + ((u >> 16) & 1u)) >> 16;  // RTNE
  return (u16)r;
}
static __device__ __forceinline__ float bf2f(u16 h) {
  unsigned u = ((unsigned)h) << 16;
  return __builtin_bit_cast(float, u);
}

// direct global->LDS DMA, 16B per lane; LDS dest is wave-uniform base + lane*16
static __device__ __forceinline__ void gload_lds16(const u16* g, u16* l) {
  __builtin_amdgcn_global_load_lds(
      (const __attribute__((address_space(1))) void*)g,
      (__attribute__((address_space(3))) void*)l, 16, 0, 0);
}

// ---------------- weight prep: w = g * v / ||v_row||, store [N][Kpad] bf16 ----------------
__global__ void prep_w_bf16(const float* __restrict__ v, const float* __restrict__ g,
                            u16* __restrict__ out, int fan_in, int kpad) {
  const int row = blockIdx.x;
  const int lane = threadIdx.x;
  double s = 0.0;
  for (int k = lane; k < fan_in; k += 64) {
    double x = (double)v[(size_t)row * fan_in + k];
    s += x * x;
  }
#pragma unroll
  for (int off = 32; off; off >>= 1) s += __shfl_xor(s, off);
  double scale = (double)g[row] / sqrt(s);
  for (int k = lane; k < kpad; k += 64) {
    float wv = (k < fan_in) ? (float)((double)v[(size_t)row * fan_in + k] * scale) : 0.0f;
    out[(size_t)row * kpad + k] = f2bf(wv);
  }
}

__global__ void prep_w_f32(const float* __restrict__ v, const float* __restrict__ g,
                           float* __restrict__ out, int fan_in) {
  const int row = blockIdx.x;
  const int lane = threadIdx.x;
  double s = 0.0;
  for (int k = lane; k < fan_in; k += 64) {
    double x = (double)v[(size_t)row * fan_in + k];
    s += x * x;
  }
#pragma unroll
  for (int off = 32; off; off >>= 1) s += __shfl_xor(s, off);
  double scale = (double)g[row] / sqrt(s);
  for (int k = lane; k < fan_in; k += 64) {
    out[(size_t)row * fan_in + k] = (float)((double)v[(size_t)row * fan_in + k] * scale);
  }
}

// ---------------- phase A: ball-query scan, one WAVE per point ----------------
// idxbuf row (24 u16 per point): [0:20) neighbor indices (first-20 by index), [20] count
__global__ __launch_bounds__(256) void scan_kernel(
    const float* __restrict__ pts, const float* __restrict__ phys,
    u16* __restrict__ idxbuf) {
  const int m = (int)((blockIdx.x * blockDim.x + threadIdx.x) >> 6);
  const int lane = (int)(threadIdx.x & 63);

  const double qx = (double)pts[m * 3 + 0];
  const double qy = (double)pts[m * 3 + 1];
  const double qz = (double)pts[m * 3 + 2];

  u16* __restrict__ row = idxbuf + (size_t)m * 24;

  int found = 0;
  for (int base = 0; base < 4096 && found < 20; base += 64) {
    const int j = base + lane;
    const double px = (double)phys[j * 3 + 0];
    const double py = (double)phys[j * 3 + 1];
    const double pz = (double)phys[j * 3 + 2];
    const double dx = px - qx, dy = py - qy, dz = pz - qz;
    const double d2 = dx * dx + dy * dy + dz * dz;   // fp64: selection must match np ref
    const bool valid = d2 < 81.0;
    const unsigned long long mb = __ballot(valid);
    const int rank = found + __popcll(mb & ((1ull << lane) - 1ull));
    if (valid && rank < 20) row[rank] = (u16)j;
    found += __popcll(mb);
    if (found > 20) found = 20;
  }
  if (lane == 0) row[20] = (u16)found;
}

// ---------------- phase B: gather + stats, one LANE per point, fixed 20 slots ----------------
// Pbuf layout per point (12 f32): density, spx,spy,spz, vax,vay,vaz, sdx,sdy,sdz, 0,0
__global__ __launch_bounds__(256) void gstats_kernel(
    const float* __restrict__ pts, const float* __restrict__ phys,
    const float* __restrict__ cam, const u16* __restrict__ idxbuf,
    float* __restrict__ Pbuf) {
  const int i = blockIdx.x * 256 + threadIdx.x;

  const double qx = (double)pts[i * 3 + 0];
  const double qy = (double)pts[i * 3 + 1];
  const double qz = (double)pts[i * 3 + 2];

  const u16* __restrict__ row = idxbuf + (size_t)i * 24;
  const int cnt = (int)row[20];

  int nnn = 0;
  double w_sum = 0, wpx = 0, wpy = 0, wpz = 0;
  double Sx = 0, Sy = 0, Sz = 0, Qx = 0, Qy = 0, Qz = 0;

#pragma unroll
  for (int s = 0; s < 20; ++s) {
    if (s < cnt) {
      const int j = (int)row[s];
      const double px = (double)phys[j * 3 + 0];
      const double py = (double)phys[j * 3 + 1];
      const double pz = (double)phys[j * 3 + 2];
      const double dx = px - qx, dy = py - qy, dz = pz - qz;
      const double d2 = dx * dx + dy * dy + dz * dz;
      const float d2f = (float)d2;
      float wf = 1.0f - d2f * sqrtf(d2f) * (1.0f / 729.0f);
      if (wf < 0.0f) wf = 0.0f;
      const double w = (double)wf;
      w_sum += w; wpx += w * px; wpy += w * py; wpz += w * pz;
      if (d2 != 0.0) {
        nnn += 1;
        Sx += dx; Sy += dy; Sz += dz;
        Qx += dx * dx; Qy += dy * dy; Qz += dz * dz;
      }
    }
  }

  // padding slots: neighbors = 0 -> dd = ||q||
  {
    const float q2f = (float)(qx * qx + qy * qy + qz * qz);
    float wpad = 1.0f - q2f * sqrtf(q2f) * (1.0f / 729.0f);
    if (wpad < 0.0f) wpad = 0.0f;
    w_sum += (double)(20 - cnt) * (double)wpad;
  }

  const double inv_denom = 1.0 / (w_sum + 1e-12);
  const double sposx = wpx * inv_denom, sposy = wpy * inv_denom, sposz = wpz * inv_denom;

  const double inv_nd = 1.0 / ((double)nnn + 1e-12);
  const double vmx = Sx * inv_nd, vmy = Sy * inv_nd, vmz = Sz * inv_nd;
  const float vax = (float)((Qx - 2.0 * vmx * Sx + (double)nnn * vmx * vmx) * inv_nd);
  const float vay = (float)((Qy - 2.0 * vmy * Sy + (double)nnn * vmy * vmy) * inv_nd);
  const float vaz = (float)((Qz - 2.0 * vmz * Sz + (double)nnn * vmz * vmz) * inv_nd);

  const double ddx = sposx - (double)cam[0];
  const double ddy = sposy - (double)cam[1];
  const double ddz = sposz - (double)cam[2];
  const double inv_dnm = 1.0 / sqrt(ddx * ddx + ddy * ddy + ddz * ddz);

  f32x4* out = (f32x4*)(Pbuf + (size_t)i * 12);
  f32x4 o0, o1, o2;
  o0[0] = (float)w_sum; o0[1] = (float)sposx; o0[2] = (float)sposy; o0[3] = (float)sposz;
  o1[0] = vax; o1[1] = vay; o1[2] = vaz; o1[3] = (float)(ddx * inv_dnm);
  o2[0] = (float)(ddy * inv_dnm); o2[1] = (float)(ddz * inv_dnm); o2[2] = 0.0f; o2[3] = 0.0f;
  out[0] = o0; out[1] = o1; out[2] = o2;
}

// ---------------- plan table for X columns ----------------
// plan[k] u32: src(bits 0-4) | op(bits 8-10) | fexp(bits 12-16)
// op: 0=copy scalar, 1=sin, 2=cos, 3=fv, 4=zero
// scalar slots: 0-2 pts, 3-5 vdir, 6-8 nrm, 9 density, 10-12 spos, 13-15 var,
//               16-18 ray_dir, 19-21 sdir
__global__ void build_plan(unsigned* __restrict__ plan) {
  const int k = blockIdx.x * 64 + threadIdx.x;
  if (k >= 576) return;
  unsigned p;
  if (k < 9) {
    p = (unsigned)k;                       // copy, src=k
  } else if (k < 265) {
    p = 3u << 8;                           // fv
  } else if (k >= 328 && k < 337) {        // embed1(density)
    int e = k - 328;
    if (e == 0) p = 9u;
    else {
      int u = e - 1;
      p = 9u | (((u & 1) ? 2u : 1u) << 8) | ((unsigned)(u >> 1) << 12);
    }
  } else if (k < 517) {                    // embed3 regions
    int e, src0;
    if (k < 328)      { e = k - 265; src0 = 0;  }
    else if (k < 400) { e = k - 337; src0 = 10; }
    else if (k < 463) { e = k - 400; src0 = 13; }
    else if (k < 490) { e = k - 463; src0 = 16; }
    else              { e = k - 490; src0 = 19; }
    if (e < 3) p = (unsigned)(src0 + e);
    else {
      int u = e - 3, f = u / 6, r = u - f * 6, ci = r % 3;
      p = (unsigned)(src0 + ci) | (((r < 3) ? 1u : 2u) << 8) | ((unsigned)f << 12);
    }
  } else {
    p = 4u << 8;                           // zero pad
  }
  plan[k] = p;
}

// ---------------- embed + write X: one wave per point, plan-driven ----------------
__global__ __launch_bounds__(256) void emb_kernel(
    const float* __restrict__ pts, const float* __restrict__ nrm,
    const float* __restrict__ vdir, const float* __restrict__ fv,
    const float* __restrict__ rdir, const float* __restrict__ Pbuf,
    const unsigned* __restrict__ plan, u16* __restrict__ X) {
  const int m = (int)((blockIdx.x * blockDim.x + threadIdx.x) >> 6);
  const int lane = (int)(threadIdx.x & 63);
  const int wv = (int)(threadIdx.x >> 6);

  __shared__ float sc[4][24];
  if (lane < 3) {
    const int ray = m >> 7;  // reps = 32768/256 = 128
    sc[wv][lane] = pts[m * 3 + lane];
    sc[wv][3 + lane] = vdir[m * 3 + lane];
    sc[wv][6 + lane] = nrm[m * 3 + lane];
    sc[wv][16 + lane] = rdir[ray * 3 + lane];
  }
  if (lane < 10) {
    // Pbuf: 0 density -> 9; 1..3 spos -> 10..12; 4..6 var -> 13..15; 7..9 sdir -> 19..21
    sc[wv][lane < 7 ? 9 + lane : 12 + lane] = Pbuf[(size_t)m * 12 + lane];
  }
  __syncthreads();

  u16* __restrict__ xrow = X + (size_t)m * 576;
#pragma unroll
  for (int it = 0; it < 9; ++it) {
    const int k = it * 64 + lane;
    const unsigned p = plan[k];
    const unsigned op = (p >> 8) & 7u;
    float val;
    if (op == 3u) {
      val = fv[(size_t)m * 256 + (k - 9)];
    } else if (op == 4u) {
      val = 0.0f;
    } else {
      float x = sc[wv][p & 31u];
      x *= __builtin_bit_cast(float, (127u + ((p >> 12) & 31u)) << 23);  // *2^fexp
      if (op == 0u) {
        val = x;
      } else {
        float r = x * 0.15915494309189535f;          // revolutions
        if (op == 2u) r += 0.25f;                    // cos = sin(+1/4 rev)
        r -= floorf(r);
        val = __builtin_amdgcn_sinf(r);
      }
    }
    xrow[k] = f2bf(val);
  }
}

// ---------------- bf16 MFMA GEMM: C[M,512] = relu(A[M,K] * B[N,K]^T + bias) ----------------
// m97 structure: tile 128x128, BK=64, 4 waves (2x2), global_load_lds staging,
// linear LDS [128][64] (DMA writes wave-uniform base + lane*16 -> no padding allowed).
template <int KTILES>
__global__ __launch_bounds__(256) void gemm_relu(const u16* __restrict__ A,
                                                 const u16* __restrict__ B,
                                                 const float* __restrict__ bias,
                                                 u16* __restrict__ C) {
  constexpr int K = KTILES * 64;
  __shared__ __align__(16) u16 As[128][64];
  __shared__ __align__(16) u16 Bs[128][64];

  const int t = threadIdx.x;
  const int lane = t & 63;
  const int wid = t >> 6;
  const int wm = wid >> 1, wn = wid & 1;
  const int n0 = blockIdx.x * 128;
  const int m0 = blockIdx.y * 128;

  // staging geometry: wave wid covers rows [wid*32, wid*32+32), 4 issues of 8 rows
  const int srow = lane >> 3;          // 0..7 within an 8-row group
  const int scol = (lane & 7) * 8;     // element column (16B chunks)

  f32x4 acc[4][4] = {};

  for (int kt = 0; kt < KTILES; ++kt) {
    const int k0 = kt * 64;
    __syncthreads();  // previous tile fully consumed
#pragma unroll
    for (int i = 0; i < 4; ++i) {
      const int rbase = wid * 32 + i * 8;
      const int row = rbase + srow;
      gload_lds16(A + (size_t)(m0 + row) * K + k0 + scol, &As[rbase][0]);
      gload_lds16(B + (size_t)(n0 + row) * K + k0 + scol, &Bs[rbase][0]);
    }
    __syncthreads();  // compiler drains vmcnt(0) before s_barrier -> LDS ready
#pragma unroll
    for (int ks = 0; ks < 2; ++ks) {
      short8 af[4], bfv[4];
#pragma unroll
      for (int f = 0; f < 4; ++f) {
        af[f] = *(const short8*)&As[wm * 64 + f * 16 + (lane & 15)][ks * 32 + (lane >> 4) * 8];
        bfv[f] = *(const short8*)&Bs[wn * 64 + f * 16 + (lane & 15)][ks * 32 + (lane >> 4) * 8];
      }
#pragma unroll
      for (int fm = 0; fm < 4; ++fm)
#pragma unroll
        for (int fn = 0; fn < 4; ++fn)
          acc[fm][fn] = __builtin_amdgcn_mfma_f32_16x16x32_bf16(af[fm], bfv[fn], acc[fm][fn], 0, 0, 0);
    }
  }

  // epilogue: D layout col=lane&15, row=(lane>>4)*4+reg
  const int lr = lane >> 4, lc = lane & 15;
#pragma unroll
  for (int fn = 0; fn < 4; ++fn) {
    const int col = n0 + wn * 64 + fn * 16 + lc;
    const float bv = bias[col];
#pragma unroll
    for (int fm = 0; fm < 4; ++fm) {
      const int rowb = m0 + wm * 64 + fm * 16 + lr * 4;
#pragma unroll
      for (int rg = 0; rg < 4; ++rg) {
        float vv = acc[fm][fn][rg] + bv;
        vv = fmaxf(vv, 0.0f);
        C[(size_t)(rowb + rg) * 512 + col] = f2bf(vv);
      }
    }
  }
}

// ---------------- final layer 512->3 + sigmoid, one wave per point ----------------
__global__ __launch_bounds__(256) void final_kernel(const u16* __restrict__ H,
                                                    const float* __restrict__ W4,
                                                    const float* __restrict__ b4,
                                                    float* __restrict__ out) {
  const int m = (int)((blockIdx.x * blockDim.x + threadIdx.x) >> 6);
  const int lane = (int)(threadIdx.x & 63);

  short8 hv = *(const short8*)(H + (size_t)m * 512 + lane * 8);
  float x[8];
#pragma unroll
  for (int e = 0; e < 8; ++e) x[e] = bf2f((u16)hv[e]);

  float s0 = 0, s1 = 0, s2 = 0;
  const float* w0 = W4 + 0 * 512 + lane * 8;
  const float* w1 = W4 + 1 * 512 + lane * 8;
  const float* w2 = W4 + 2 * 512 + lane * 8;
#pragma unroll
  for (int e = 0; e < 8; ++e) {
    s0 += x[e] * w0[e];
    s1 += x[e] * w1[e];
    s2 += x[e] * w2[e];
  }
#pragma unroll
  for (int off = 32; off; off >>= 1) {
    s0 += __shfl_xor(s0, off);
    s1 += __shfl_xor(s1, off);
    s2 += __shfl_xor(s2, off);
  }
  if (lane < 3) {
    float v = (lane == 0) ? s0 : (lane == 1 ? s1 : s2);
    v += b4[lane];
    out[(size_t)m * 3 + lane] = 1.0f / (1.0f + expf(-v));
  }
}

// ---------------- launch ----------------
extern "C" void kernel_launch(void* const* d_in, const int* in_sizes, int n_in,
                              void* d_out, int out_size, void* d_ws, size_t ws_size,
                              hipStream_t stream) {
  const float* pts  = (const float*)d_in[0];
  const float* nrm  = (const float*)d_in[1];
  const float* vdir = (const float*)d_in[2];
  const float* fv   = (const float*)d_in[3];
  const float* phys = (const float*)d_in[4];
  const float* rdir = (const float*)d_in[5];
  const float* cam  = (const float*)d_in[6];
  const float* v0 = (const float*)d_in[7];  const float* g0 = (const float*)d_in[8];  const float* b0 = (const float*)d_in[9];
  const float* v1 = (const float*)d_in[10]; const float* g1 = (const float*)d_in[11]; const float* b1 = (const float*)d_in[12];
  const float* v2 = (const float*)d_in[13]; const float* g2 = (const float*)d_in[14]; const float* b2 = (const float*)d_in[15];
  const float* v3 = (const float*)d_in[16]; const float* g3 = (const float*)d_in[17]; const float* b3 = (const float*)d_in[18];
  const float* v4 = (const float*)d_in[19]; const float* g4 = (const float*)d_in[20]; const float* b4 = (const float*)d_in[21];

  char* ws = (char*)d_ws;
  // layout (bytes):
  u16*      W0 = (u16*)(ws + 0);          // 512*576*2 = 589824
  u16*      W1 = (u16*)(ws + 589824);     // 512*512*2 = 524288
  u16*      W2 = (u16*)(ws + 1114112);
  u16*      W3 = (u16*)(ws + 1638400);
  float*    W4 = (float*)(ws + 2162688);  // 3*512*4 = 6144
  unsigned* Pl = (unsigned*)(ws + 2168832); // 576*4 = 2304
  u16*      Ix = (u16*)(ws + 2171136);    // 32768*24*2 = 1572864
  float*    Pb = (float*)(ws + 3744000);  // 32768*12*4 = 1572864
  u16*      X  = (u16*)(ws + 5316864);    // 32768*576*2 = 37748736
  u16*      H1 = (u16*)(ws + 43065600);   // 32768*512*2 = 33554432
  u16*      H2 = X;  // X not needed after layer 0; reuse as ping-pong buffer

  prep_w_bf16<<<512, 64, 0, stream>>>(v0, g0, W0, 517, 576);
  prep_w_bf16<<<512, 64, 0, stream>>>(v1, g1, W1, 512, 512);
  prep_w_bf16<<<512, 64, 0, stream>>>(v2, g2, W2, 512, 512);
  prep_w_bf16<<<512, 64, 0, stream>>>(v3, g3, W3, 512, 512);
  prep_w_f32<<<3, 64, 0, stream>>>(v4, g4, W4, 512);
  build_plan<<<9, 64, 0, stream>>>(Pl);

  scan_kernel<<<8192, 256, 0, stream>>>(pts, phys, Ix);
  gstats_kernel<<<128, 256, 0, stream>>>(pts, phys, cam, Ix, Pb);
  emb_kernel<<<8192, 256, 0, stream>>>(pts, nrm, vdir, fv, rdir, Pb, Pl, X);

  gemm_relu<9><<<dim3(4, 256), 256, 0, stream>>>(X,  W0, b0, H1);
  gemm_relu<8><<<dim3(4, 256), 256, 0, stream>>>(H1, W1, b1, H2);
  gemm_relu<8><<<dim3(4, 256), 256, 0, stream>>>(H2, W2, b2, H1);
  gemm_relu<8><<<dim3(4, 256), 256, 0, stream>>>(H1, W3, b3, H2);

  final_kernel<<<8192, 256, 0, stream>>>(H2, W4, b4, (float*)d_out);
}

// Round 6
// 180.893 us; speedup vs baseline: 1.2099x; 1.2099x over previous
//
#include <hip/hip_runtime.h>
#include <hip/hip_bf16.h>

typedef unsigned short u16;
typedef short short8 __attribute__((ext_vector_type(8)));
typedef float f32x4 __attribute__((ext_vector_type(4)));

// ---------------- helpers ----------------
static __device__ __forceinline__ u16 f2bf(float f) {
  unsigned u = __builtin_bit_cast(unsigned, f);
  unsigned r = (u + 0x7fffu + ((u >> 16) & 1u)) >> 16;  // RTNE
  return (u16)r;
}
static __device__ __forceinline__ float bf2f(u16 h) {
  unsigned u = ((unsigned)h) << 16;
  return __builtin_bit_cast(float, u);
}

// direct global->LDS DMA, 16B per lane; LDS dest is wave-uniform base + lane*16
static __device__ __forceinline__ void gload_lds16(const u16* g, u16* l) {
  __builtin_amdgcn_global_load_lds(
      (const __attribute__((address_space(1))) void*)g,
      (__attribute__((address_space(3))) void*)l, 16, 0, 0);
}

// ---------------- weight prep: w = g * v / ||v_row||, store [N][Kpad] bf16 ----------------
__global__ void prep_w_bf16(const float* __restrict__ v, const float* __restrict__ g,
                            u16* __restrict__ out, int fan_in, int kpad) {
  const int row = blockIdx.x;
  const int lane = threadIdx.x;
  double s = 0.0;
  for (int k = lane; k < fan_in; k += 64) {
    double x = (double)v[(size_t)row * fan_in + k];
    s += x * x;
  }
#pragma unroll
  for (int off = 32; off; off >>= 1) s += __shfl_xor(s, off);
  double scale = (double)g[row] / sqrt(s);
  for (int k = lane; k < kpad; k += 64) {
    float wv = (k < fan_in) ? (float)((double)v[(size_t)row * fan_in + k] * scale) : 0.0f;
    out[(size_t)row * kpad + k] = f2bf(wv);
  }
}

__global__ void prep_w_f32(const float* __restrict__ v, const float* __restrict__ g,
                           float* __restrict__ out, int fan_in) {
  const int row = blockIdx.x;
  const int lane = threadIdx.x;
  double s = 0.0;
  for (int k = lane; k < fan_in; k += 64) {
    double x = (double)v[(size_t)row * fan_in + k];
    s += x * x;
  }
#pragma unroll
  for (int off = 32; off; off >>= 1) s += __shfl_xor(s, off);
  double scale = (double)g[row] / sqrt(s);
  for (int k = lane; k < fan_in; k += 64) {
    out[(size_t)row * fan_in + k] = (float)((double)v[(size_t)row * fan_in + k] * scale);
  }
}

// ---------------- phase A: ball-query scan, one WAVE per point ----------------
// idxbuf row (24 u16 per point): [0:20) neighbor indices (first-20 by index), [20] count
__global__ __launch_bounds__(256) void scan_kernel(
    const float* __restrict__ pts, const float* __restrict__ phys,
    u16* __restrict__ idxbuf) {
  const int m = (int)((blockIdx.x * blockDim.x + threadIdx.x) >> 6);
  const int lane = (int)(threadIdx.x & 63);

  const double qx = (double)pts[m * 3 + 0];
  const double qy = (double)pts[m * 3 + 1];
  const double qz = (double)pts[m * 3 + 2];

  u16* __restrict__ row = idxbuf + (size_t)m * 24;

  int found = 0;
  for (int base = 0; base < 4096 && found < 20; base += 64) {
    const int j = base + lane;
    const double px = (double)phys[j * 3 + 0];
    const double py = (double)phys[j * 3 + 1];
    const double pz = (double)phys[j * 3 + 2];
    const double dx = px - qx, dy = py - qy, dz = pz - qz;
    const double d2 = dx * dx + dy * dy + dz * dz;   // fp64: selection must match np ref
    const bool valid = d2 < 81.0;
    const unsigned long long mb = __ballot(valid);
    const int rank = found + __popcll(mb & ((1ull << lane) - 1ull));
    if (valid && rank < 20) row[rank] = (u16)j;
    found += __popcll(mb);
    if (found > 20) found = 20;
  }
  if (lane == 0) row[20] = (u16)found;
}

// ---------------- phase B: gather + stats, one LANE per point, fixed 20 slots ----------------
// Pbuf layout per point (12 f32): density, spx,spy,spz, vax,vay,vaz, sdx,sdy,sdz, 0,0
__global__ __launch_bounds__(256) void gstats_kernel(
    const float* __restrict__ pts, const float* __restrict__ phys,
    const float* __restrict__ cam, const u16* __restrict__ idxbuf,
    float* __restrict__ Pbuf) {
  const int i = blockIdx.x * 256 + threadIdx.x;

  const double qx = (double)pts[i * 3 + 0];
  const double qy = (double)pts[i * 3 + 1];
  const double qz = (double)pts[i * 3 + 2];

  const u16* __restrict__ row = idxbuf + (size_t)i * 24;
  const int cnt = (int)row[20];

  int nnn = 0;
  double w_sum = 0, wpx = 0, wpy = 0, wpz = 0;
  double Sx = 0, Sy = 0, Sz = 0, Qx = 0, Qy = 0, Qz = 0;

#pragma unroll
  for (int s = 0; s < 20; ++s) {
    if (s < cnt) {
      const int j = (int)row[s];
      const double px = (double)phys[j * 3 + 0];
      const double py = (double)phys[j * 3 + 1];
      const double pz = (double)phys[j * 3 + 2];
      const double dx = px - qx, dy = py - qy, dz = pz - qz;
      const double d2 = dx * dx + dy * dy + dz * dz;
      const float d2f = (float)d2;
      float wf = 1.0f - d2f * sqrtf(d2f) * (1.0f / 729.0f);
      if (wf < 0.0f) wf = 0.0f;
      const double w = (double)wf;
      w_sum += w; wpx += w * px; wpy += w * py; wpz += w * pz;
      if (d2 != 0.0) {
        nnn += 1;
        Sx += dx; Sy += dy; Sz += dz;
        Qx += dx * dx; Qy += dy * dy; Qz += dz * dz;
      }
    }
  }

  // padding slots: neighbors = 0 -> dd = ||q||
  {
    const float q2f = (float)(qx * qx + qy * qy + qz * qz);
    float wpad = 1.0f - q2f * sqrtf(q2f) * (1.0f / 729.0f);
    if (wpad < 0.0f) wpad = 0.0f;
    w_sum += (double)(20 - cnt) * (double)wpad;
  }

  const double inv_denom = 1.0 / (w_sum + 1e-12);
  const double sposx = wpx * inv_denom, sposy = wpy * inv_denom, sposz = wpz * inv_denom;

  const double inv_nd = 1.0 / ((double)nnn + 1e-12);
  const double vmx = Sx * inv_nd, vmy = Sy * inv_nd, vmz = Sz * inv_nd;
  const float vax = (float)((Qx - 2.0 * vmx * Sx + (double)nnn * vmx * vmx) * inv_nd);
  const float vay = (float)((Qy - 2.0 * vmy * Sy + (double)nnn * vmy * vmy) * inv_nd);
  const float vaz = (float)((Qz - 2.0 * vmz * Sz + (double)nnn * vmz * vmz) * inv_nd);

  const double ddx = sposx - (double)cam[0];
  const double ddy = sposy - (double)cam[1];
  const double ddz = sposz - (double)cam[2];
  const double inv_dnm = 1.0 / sqrt(ddx * ddx + ddy * ddy + ddz * ddz);

  f32x4* out = (f32x4*)(Pbuf + (size_t)i * 12);
  f32x4 o0, o1, o2;
  o0[0] = (float)w_sum; o0[1] = (float)sposx; o0[2] = (float)sposy; o0[3] = (float)sposz;
  o1[0] = vax; o1[1] = vay; o1[2] = vaz; o1[3] = (float)(ddx * inv_dnm);
  o2[0] = (float)(ddy * inv_dnm); o2[1] = (float)(ddz * inv_dnm); o2[2] = 0.0f; o2[3] = 0.0f;
  out[0] = o0; out[1] = o1; out[2] = o2;
}

// ---------------- plan table for X columns ----------------
// plan[k] u32: src(bits 0-4) | op(bits 8-10) | fexp(bits 12-16)
// op: 0=copy scalar, 1=sin, 2=cos, 3=fv, 4=zero
// scalar slots: 0-2 pts, 3-5 vdir, 6-8 nrm, 9 density, 10-12 spos, 13-15 var,
//               16-18 ray_dir, 19-21 sdir
__global__ void build_plan(unsigned* __restrict__ plan) {
  const int k = blockIdx.x * 64 + threadIdx.x;
  if (k >= 576) return;
  unsigned p;
  if (k < 9) {
    p = (unsigned)k;                       // copy, src=k
  } else if (k < 265) {
    p = 3u << 8;                           // fv
  } else if (k >= 328 && k < 337) {        // embed1(density)
    int e = k - 328;
    if (e == 0) p = 9u;
    else {
      int u = e - 1;
      p = 9u | (((u & 1) ? 2u : 1u) << 8) | ((unsigned)(u >> 1) << 12);
    }
  } else if (k < 517) {                    // embed3 regions
    int e, src0;
    if (k < 328)      { e = k - 265; src0 = 0;  }
    else if (k < 400) { e = k - 337; src0 = 10; }
    else if (k < 463) { e = k - 400; src0 = 13; }
    else if (k < 490) { e = k - 463; src0 = 16; }
    else              { e = k - 490; src0 = 19; }
    if (e < 3) p = (unsigned)(src0 + e);
    else {
      int u = e - 3, f = u / 6, r = u - f * 6, ci = r % 3;
      p = (unsigned)(src0 + ci) | (((r < 3) ? 1u : 2u) << 8) | ((unsigned)f << 12);
    }
  } else {
    p = 4u << 8;                           // zero pad
  }
  plan[k] = p;
}

// ---------------- embed + write X: one wave per point, plan-driven ----------------
__global__ __launch_bounds__(256) void emb_kernel(
    const float* __restrict__ pts, const float* __restrict__ nrm,
    const float* __restrict__ vdir, const float* __restrict__ fv,
    const float* __restrict__ rdir, const float* __restrict__ Pbuf,
    const unsigned* __restrict__ plan, u16* __restrict__ X) {
  const int m = (int)((blockIdx.x * blockDim.x + threadIdx.x) >> 6);
  const int lane = (int)(threadIdx.x & 63);
  const int wv = (int)(threadIdx.x >> 6);

  __shared__ float sc[4][24];
  if (lane < 3) {
    const int ray = m >> 7;  // reps = 32768/256 = 128
    sc[wv][lane] = pts[m * 3 + lane];
    sc[wv][3 + lane] = vdir[m * 3 + lane];
    sc[wv][6 + lane] = nrm[m * 3 + lane];
    sc[wv][16 + lane] = rdir[ray * 3 + lane];
  }
  if (lane < 10) {
    // Pbuf: 0 density -> 9; 1..3 spos -> 10..12; 4..6 var -> 13..15; 7..9 sdir -> 19..21
    sc[wv][lane < 7 ? 9 + lane : 12 + lane] = Pbuf[(size_t)m * 12 + lane];
  }
  __syncthreads();

  u16* __restrict__ xrow = X + (size_t)m * 576;
#pragma unroll
  for (int it = 0; it < 9; ++it) {
    const int k = it * 64 + lane;
    const unsigned p = plan[k];
    const unsigned op = (p >> 8) & 7u;
    float val;
    if (op == 3u) {
      val = fv[(size_t)m * 256 + (k - 9)];
    } else if (op == 4u) {
      val = 0.0f;
    } else {
      float x = sc[wv][p & 31u];
      x *= __builtin_bit_cast(float, (127u + ((p >> 12) & 31u)) << 23);  // *2^fexp
      if (op == 0u) {
        val = x;
      } else {
        float r = x * 0.15915494309189535f;          // revolutions
        if (op == 2u) r += 0.25f;                    // cos = sin(+1/4 rev)
        r -= floorf(r);
        val = __builtin_amdgcn_sinf(r);
      }
    }
    xrow[k] = f2bf(val);
  }
}

// ---------------- bf16 MFMA GEMM: C[M,512] = relu(A[M,K] * B[N,K]^T + bias) ----------------
// 128x128 tile, BK=64, 4 waves (2x2). Double-buffered gload_lds staging with
// counted vmcnt (T4): STAGE(kt+1) issued before compute(kt); vmcnt(8) waits only
// the previous tile's 8 DMAs. Raw s_barrier (NOT __syncthreads -> no forced
// vmcnt(0) drain). Both-sides XOR swizzle (rule #21): DMA source chunk and
// ds_read chunk both ^= (row&7) -> bank-conflict-free reads.
template <int KTILES>
__global__ __launch_bounds__(256) void gemm_relu(const u16* __restrict__ A,
                                                 const u16* __restrict__ B,
                                                 const float* __restrict__ bias,
                                                 u16* __restrict__ C) {
  constexpr int K = KTILES * 64;
  __shared__ __align__(16) u16 As[2][128][64];
  __shared__ __align__(16) u16 Bs[2][128][64];

  const int t = threadIdx.x;
  const int lane = t & 63;
  const int wid = t >> 6;
  const int wm = wid >> 1, wn = wid & 1;

  // XCD-aware bijective swizzle: 1024 blocks, 8 XCDs -> each XCD gets 32
  // contiguous m-tiles with all 4 n-tiles (A-panel L2 reuse within one XCD).
  const int bid = blockIdx.x;
  const int wgid = (bid & 7) * 128 + (bid >> 3);   // nwg=1024 divisible by 8
  const int n0 = (wgid & 3) * 128;
  const int m0 = (wgid >> 2) * 128;

  // staging geometry: wave wid covers rows [wid*32, wid*32+32), 4 slabs of 8 rows;
  // each lane fetches the swizzled global chunk (lane&7)^(lane>>3) of its row.
  const int srow = lane >> 3;                      // 0..7 within an 8-row slab
  const int gcol = ((lane & 7) ^ srow) * 8;        // swizzled source chunk

  f32x4 acc[4][4] = {};

#define STAGE(kt, b)                                                            \
  {                                                                             \
    const int k0_ = (kt) * 64;                                                  \
    _Pragma("unroll")                                                           \
    for (int i_ = 0; i_ < 4; ++i_) {                                            \
      const int rbase_ = wid * 32 + i_ * 8;                                     \
      const int row_ = rbase_ + srow;                                           \
      gload_lds16(A + (size_t)(m0 + row_) * K + k0_ + gcol, &As[b][rbase_][0]); \
      gload_lds16(B + (size_t)(n0 + row_) * K + k0_ + gcol, &Bs[b][rbase_][0]); \
    }                                                                           \
  }

  STAGE(0, 0);

  const int rsw = lane & 7;  // frag row & 7  (rows are wm*64+f*16+(lane&15))
  for (int kt = 0; kt < KTILES; ++kt) {
    const int cur = kt & 1;
    __builtin_amdgcn_s_barrier();                 // (a) prev-buf reads all done
    if (kt + 1 < KTILES) {
      STAGE(kt + 1, cur ^ 1);
      asm volatile("s_waitcnt vmcnt(8)" ::: "memory");   // wait tile-kt DMAs only
    } else {
      asm volatile("s_waitcnt vmcnt(0)" ::: "memory");   // last tile: full drain
    }
    __builtin_amdgcn_s_barrier();                 // (b) everyone's buf[cur] ready
#pragma unroll
    for (int ks = 0; ks < 2; ++ks) {
      short8 af[4], bfv[4];
#pragma unroll
      for (int f = 0; f < 4; ++f) {
        const int ar = wm * 64 + f * 16 + (lane & 15);
        const int br = wn * 64 + f * 16 + (lane & 15);
        const int cc = ((ks * 4 + (lane >> 4)) ^ rsw) * 8;  // swizzled read chunk
        af[f]  = *(const short8*)&As[cur][ar][cc];
        bfv[f] = *(const short8*)&Bs[cur][br][cc];
      }
#pragma unroll
      for (int fm = 0; fm < 4; ++fm)
#pragma unroll
        for (int fn = 0; fn < 4; ++fn)
          acc[fm][fn] = __builtin_amdgcn_mfma_f32_16x16x32_bf16(af[fm], bfv[fn], acc[fm][fn], 0, 0, 0);
    }
  }
#undef STAGE

  // epilogue: D layout col=lane&15, row=(lane>>4)*4+reg
  const int lr = lane >> 4, lc = lane & 15;
#pragma unroll
  for (int fn = 0; fn < 4; ++fn) {
    const int col = n0 + wn * 64 + fn * 16 + lc;
    const float bv = bias[col];
#pragma unroll
    for (int fm = 0; fm < 4; ++fm) {
      const int rowb = m0 + wm * 64 + fm * 16 + lr * 4;
#pragma unroll
      for (int rg = 0; rg < 4; ++rg) {
        float vv = acc[fm][fn][rg] + bv;
        vv = fmaxf(vv, 0.0f);
        C[(size_t)(rowb + rg) * 512 + col] = f2bf(vv);
      }
    }
  }
}

// ---------------- final layer 512->3 + sigmoid, one wave per point ----------------
__global__ __launch_bounds__(256) void final_kernel(const u16* __restrict__ H,
                                                    const float* __restrict__ W4,
                                                    const float* __restrict__ b4,
                                                    float* __restrict__ out) {
  const int m = (int)((blockIdx.x * blockDim.x + threadIdx.x) >> 6);
  const int lane = (int)(threadIdx.x & 63);

  short8 hv = *(const short8*)(H + (size_t)m * 512 + lane * 8);
  float x[8];
#pragma unroll
  for (int e = 0; e < 8; ++e) x[e] = bf2f((u16)hv[e]);

  float s0 = 0, s1 = 0, s2 = 0;
  const float* w0 = W4 + 0 * 512 + lane * 8;
  const float* w1 = W4 + 1 * 512 + lane * 8;
  const float* w2 = W4 + 2 * 512 + lane * 8;
#pragma unroll
  for (int e = 0; e < 8; ++e) {
    s0 += x[e] * w0[e];
    s1 += x[e] * w1[e];
    s2 += x[e] * w2[e];
  }
#pragma unroll
  for (int off = 32; off; off >>= 1) {
    s0 += __shfl_xor(s0, off);
    s1 += __shfl_xor(s1, off);
    s2 += __shfl_xor(s2, off);
  }
  if (lane < 3) {
    float v = (lane == 0) ? s0 : (lane == 1 ? s1 : s2);
    v += b4[lane];
    out[(size_t)m * 3 + lane] = 1.0f / (1.0f + expf(-v));
  }
}

// ---------------- launch ----------------
extern "C" void kernel_launch(void* const* d_in, const int* in_sizes, int n_in,
                              void* d_out, int out_size, void* d_ws, size_t ws_size,
                              hipStream_t stream) {
  const float* pts  = (const float*)d_in[0];
  const float* nrm  = (const float*)d_in[1];
  const float* vdir = (const float*)d_in[2];
  const float* fv   = (const float*)d_in[3];
  const float* phys = (const float*)d_in[4];
  const float* rdir = (const float*)d_in[5];
  const float* cam  = (const float*)d_in[6];
  const float* v0 = (const float*)d_in[7];  const float* g0 = (const float*)d_in[8];  const float* b0 = (const float*)d_in[9];
  const float* v1 = (const float*)d_in[10]; const float* g1 = (const float*)d_in[11]; const float* b1 = (const float*)d_in[12];
  const float* v2 = (const float*)d_in[13]; const float* g2 = (const float*)d_in[14]; const float* b2 = (const float*)d_in[15];
  const float* v3 = (const float*)d_in[16]; const float* g3 = (const float*)d_in[17]; const float* b3 = (const float*)d_in[18];
  const float* v4 = (const float*)d_in[19]; const float* g4 = (const float*)d_in[20]; const float* b4 = (const float*)d_in[21];

  char* ws = (char*)d_ws;
  // layout (bytes):
  u16*      W0 = (u16*)(ws + 0);          // 512*576*2 = 589824
  u16*      W1 = (u16*)(ws + 589824);     // 512*512*2 = 524288
  u16*      W2 = (u16*)(ws + 1114112);
  u16*      W3 = (u16*)(ws + 1638400);
  float*    W4 = (float*)(ws + 2162688);  // 3*512*4 = 6144
  unsigned* Pl = (unsigned*)(ws + 2168832); // 576*4 = 2304
  u16*      Ix = (u16*)(ws + 2171136);    // 32768*24*2 = 1572864
  float*    Pb = (float*)(ws + 3744000);  // 32768*12*4 = 1572864
  u16*      X  = (u16*)(ws + 5316864);    // 32768*576*2 = 37748736
  u16*      H1 = (u16*)(ws + 43065600);   // 32768*512*2 = 33554432
  u16*      H2 = X;  // X not needed after layer 0; reuse as ping-pong buffer

  prep_w_bf16<<<512, 64, 0, stream>>>(v0, g0, W0, 517, 576);
  prep_w_bf16<<<512, 64, 0, stream>>>(v1, g1, W1, 512, 512);
  prep_w_bf16<<<512, 64, 0, stream>>>(v2, g2, W2, 512, 512);
  prep_w_bf16<<<512, 64, 0, stream>>>(v3, g3, W3, 512, 512);
  prep_w_f32<<<3, 64, 0, stream>>>(v4, g4, W4, 512);
  build_plan<<<9, 64, 0, stream>>>(Pl);

  scan_kernel<<<8192, 256, 0, stream>>>(pts, phys, Ix);
  gstats_kernel<<<128, 256, 0, stream>>>(pts, phys, cam, Ix, Pb);
  emb_kernel<<<8192, 256, 0, stream>>>(pts, nrm, vdir, fv, rdir, Pb, Pl, X);

  gemm_relu<9><<<1024, 256, 0, stream>>>(X,  W0, b0, H1);
  gemm_relu<8><<<1024, 256, 0, stream>>>(H1, W1, b1, H2);
  gemm_relu<8><<<1024, 256, 0, stream>>>(H2, W2, b2, H1);
  gemm_relu<8><<<1024, 256, 0, stream>>>(H1, W3, b3, H2);

  final_kernel<<<8192, 256, 0, stream>>>(H2, W4, b4, (float*)d_out);
}